// Round 1
// baseline (288.800 us; speedup 1.0000x reference)
//
#include <hip/hip_runtime.h>

#define DEV __device__ __forceinline__

typedef __attribute__((ext_vector_type(8))) short sv8;   // 8 x bf16 bits
typedef __attribute__((ext_vector_type(4))) short sv4;
typedef __attribute__((ext_vector_type(4))) float f32x4;
typedef sv8 frag_ab;

// ---- bf16 helpers (bit-level, round-to-nearest-even) ----
DEV short f2bf(float f) {
  unsigned u = __float_as_uint(f);
  unsigned r = (u + 0x7fffu + ((u >> 16) & 1u)) >> 16;
  return (short)r;
}
DEV float bf2f(short s) {
  return __uint_as_float(((unsigned)(unsigned short)s) << 16);
}

// ---- fp32 -> bf16 conversion, 4 elems/thread ----
__global__ __launch_bounds__(256) void cvt_kernel(const float* __restrict__ in,
                                                  short* __restrict__ out, int n4) {
  int i = blockIdx.x * 256 + threadIdx.x;
  if (i >= n4) return;
  float4 v = ((const float4*)in)[i];
  sv4 o = { f2bf(v.x), f2bf(v.y), f2bf(v.z), f2bf(v.w) };
  ((sv4*)out)[i] = o;
}

// ---- NT GEMM: C[M,N] = A[M,K] * B[N,K]^T, bf16 in, fp32 acc ----
// 128x128 tile, BK=32, 4 waves (2x2), each wave 64x64 via 4x4 MFMA frags.
template <int OUT_BF16>
__global__ __launch_bounds__(256) void gemm_nt(const short* __restrict__ A,
                                               const short* __restrict__ B,
                                               void* __restrict__ C,
                                               int M, int N, int K) {
  __shared__ short As[128][40];  // +8 pad: row stride 80B, conflict-free-ish
  __shared__ short Bs[128][40];
  const int tid = threadIdx.x;
  const int wave = tid >> 6, lane = tid & 63;
  const int wr = wave >> 1, wc = wave & 1;
  const int row0 = blockIdx.x * 128, col0 = blockIdx.y * 128;
  const int rsel = lane & 15, koff = (lane >> 4) * 8;

  const f32x4 z = {0.f, 0.f, 0.f, 0.f};
  f32x4 acc[4][4];
#pragma unroll
  for (int m = 0; m < 4; ++m)
#pragma unroll
    for (int n = 0; n < 4; ++n) acc[m][n] = z;

  for (int k0 = 0; k0 < K; k0 += 32) {
#pragma unroll
    for (int s = 0; s < 2; ++s) {
      int lin = tid + s * 256;
      int r = lin >> 2;
      int c8 = (lin & 3) * 8;
      sv8 va = {0, 0, 0, 0, 0, 0, 0, 0};
      int gr = row0 + r;
      if (gr < M) va = *(const sv8*)(A + (size_t)gr * K + k0 + c8);
      *(sv8*)(&As[r][c8]) = va;
      sv8 vb = {0, 0, 0, 0, 0, 0, 0, 0};
      int gc = col0 + r;
      if (gc < N) vb = *(const sv8*)(B + (size_t)gc * K + k0 + c8);
      *(sv8*)(&Bs[r][c8]) = vb;
    }
    __syncthreads();
    frag_ab a[4], b[4];
#pragma unroll
    for (int m = 0; m < 4; ++m) a[m] = *(const frag_ab*)(&As[wr * 64 + m * 16 + rsel][koff]);
#pragma unroll
    for (int n = 0; n < 4; ++n) b[n] = *(const frag_ab*)(&Bs[wc * 64 + n * 16 + rsel][koff]);
#pragma unroll
    for (int m = 0; m < 4; ++m)
#pragma unroll
      for (int n = 0; n < 4; ++n)
        acc[m][n] = __builtin_amdgcn_mfma_f32_16x16x32_bf16(a[m], b[n], acc[m][n], 0, 0, 0);
    __syncthreads();
  }

  const int cc = lane & 15, cr = (lane >> 4) * 4;
#pragma unroll
  for (int m = 0; m < 4; ++m)
#pragma unroll
    for (int n = 0; n < 4; ++n) {
      int c = col0 + wc * 64 + n * 16 + cc;
#pragma unroll
      for (int j = 0; j < 4; ++j) {
        int r = row0 + wr * 64 + m * 16 + cr + j;
        if (r < M && c < N) {
          float v = acc[m][n][j];
          if (OUT_BF16) ((short*)C)[(size_t)r * N + c] = f2bf(v);
          else          ((float*)C)[(size_t)r * N + c] = v;
        }
      }
    }
}

// ---- LayerNorm over rows of 4096, in-place on bf16 ----
__global__ __launch_bounds__(256) void ln_kernel(short* __restrict__ mid,
                                                 const float* __restrict__ g,
                                                 const float* __restrict__ bb) {
  const int row = blockIdx.x;
  short* p = mid + (size_t)row * 4096;
  const int tid = threadIdx.x;
  sv8 v0 = *(const sv8*)(p + tid * 16);
  sv8 v1 = *(const sv8*)(p + tid * 16 + 8);
  float x[16];
#pragma unroll
  for (int j = 0; j < 8; ++j) { x[j] = bf2f(v0[j]); x[8 + j] = bf2f(v1[j]); }
  float s = 0.f, ss = 0.f;
#pragma unroll
  for (int j = 0; j < 16; ++j) { s += x[j]; ss += x[j] * x[j]; }
#pragma unroll
  for (int off = 32; off; off >>= 1) { s += __shfl_xor(s, off); ss += __shfl_xor(ss, off); }
  __shared__ float rs[4], rss[4];
  if ((tid & 63) == 0) { rs[tid >> 6] = s; rss[tid >> 6] = ss; }
  __syncthreads();
  float S = rs[0] + rs[1] + rs[2] + rs[3];
  float SS = rss[0] + rss[1] + rss[2] + rss[3];
  const float inv_n = 1.0f / 4096.0f;
  float mu = S * inv_n;
  float var = SS * inv_n - mu * mu;
  float rstd = rsqrtf(var + 1e-5f);
  const float4* g4 = (const float4*)(g + tid * 16);
  const float4* b4 = (const float4*)(bb + tid * 16);
  float y[16];
#pragma unroll
  for (int i = 0; i < 4; ++i) {
    float4 gg = g4[i], bv = b4[i];
    y[i * 4 + 0] = (x[i * 4 + 0] - mu) * rstd * gg.x + bv.x;
    y[i * 4 + 1] = (x[i * 4 + 1] - mu) * rstd * gg.y + bv.y;
    y[i * 4 + 2] = (x[i * 4 + 2] - mu) * rstd * gg.z + bv.z;
    y[i * 4 + 3] = (x[i * 4 + 3] - mu) * rstd * gg.w + bv.w;
  }
  sv8 o0, o1;
#pragma unroll
  for (int j = 0; j < 8; ++j) { o0[j] = f2bf(y[j]); o1[j] = f2bf(y[8 + j]); }
  *(sv8*)(p + tid * 16) = o0;
  *(sv8*)(p + tid * 16 + 8) = o1;
}

// ---- fused QK^T + softmax per (b,h). q: 64x128, k: 257x128, attn fp32 out ----
__global__ __launch_bounds__(256) void attn_kernel(const short* __restrict__ qb,
                                                   const short* __restrict__ kb,
                                                   float* __restrict__ attn) {
  const int bh = blockIdx.x;  // b*6+h
  const int b = bh / 6, h = bh % 6;
  const int tid = threadIdx.x, wave = tid >> 6, lane = tid & 63;
  const int rsel = lane & 15, koff = (lane >> 4) * 8;
  __shared__ float sim_s[64][266];  // stride 266 words: write 2-way, read ~2-way

  const f32x4 z = {0.f, 0.f, 0.f, 0.f};
  f32x4 acc[4][5];
#pragma unroll
  for (int m = 0; m < 4; ++m)
#pragma unroll
    for (int i = 0; i < 5; ++i) acc[m][i] = z;

#pragma unroll
  for (int k0 = 0; k0 < 128; k0 += 32) {
    frag_ab a[4];
#pragma unroll
    for (int m = 0; m < 4; ++m)
      a[m] = *(const frag_ab*)(qb + (size_t)(b * 64 + m * 16 + rsel) * 768 + h * 128 + k0 + koff);
#pragma unroll
    for (int i = 0; i < 5; ++i) {
      int nf = wave + i * 4;  // wave-uniform
      if (nf >= 17) break;
      int j = nf * 16 + rsel;
      if (j > 256) j = 256;  // clamp, masked later
      frag_ab bf = *(const frag_ab*)(kb + (size_t)(b * 257 + j) * 768 + h * 128 + k0 + koff);
#pragma unroll
      for (int m = 0; m < 4; ++m)
        acc[m][i] = __builtin_amdgcn_mfma_f32_16x16x32_bf16(a[m], bf, acc[m][i], 0, 0, 0);
    }
  }
  const float S2 = 0.08838834764831845f;  // 1/sqrt(128) = scale^2
  const int cc = lane & 15, cr = (lane >> 4) * 4;
#pragma unroll
  for (int i = 0; i < 5; ++i) {
    int nf = wave + i * 4;
    if (nf >= 17) break;
    int col = nf * 16 + cc;
    if (col < 257) {
#pragma unroll
      for (int m = 0; m < 4; ++m)
#pragma unroll
        for (int j = 0; j < 4; ++j)
          sim_s[m * 16 + cr + j][col] = acc[m][i][j] * S2;
    }
  }
  __syncthreads();
  // softmax: 4 threads per row
  const int row = tid >> 2, sub = tid & 3;
  float mx = -1e30f;
  for (int j = sub; j < 257; j += 4) mx = fmaxf(mx, sim_s[row][j]);
  mx = fmaxf(mx, __shfl_xor(mx, 1));
  mx = fmaxf(mx, __shfl_xor(mx, 2));
  float sum = 0.f;
  for (int j = sub; j < 257; j += 4) {
    float e = __expf(sim_s[row][j] - mx);
    sim_s[row][j] = e;
    sum += e;
  }
  sum += __shfl_xor(sum, 1);
  sum += __shfl_xor(sum, 2);
  float inv = 1.f / sum;
  float* dst = attn + ((size_t)bh * 64 + row) * 257;
  for (int j = sub; j < 257; j += 4) dst[j] = sim_s[row][j] * inv;
}

// ---- t[b,h,q,r] = sum_j attn[b,h,q,j] * mid_ln[b,j,q*64+r]; one block per (b,q) ----
__global__ __launch_bounds__(256) void tk_kernel(const float* __restrict__ attn,
                                                 const short* __restrict__ mid,
                                                 float* __restrict__ t) {
  const int bq = blockIdx.x;  // b*64+q
  const int b = bq >> 6, q = bq & 63;
  const int tid = threadIdx.x;
  __shared__ short ms[257][64];
  __shared__ float as_[6][257];
  for (int lin = tid; lin < 257 * 8; lin += 256) {
    int j = lin >> 3, seg = (lin & 7) * 8;
    *(sv8*)(&ms[j][seg]) = *(const sv8*)(mid + (size_t)(b * 257 + j) * 4096 + q * 64 + seg);
  }
#pragma unroll
  for (int h = 0; h < 6; ++h)
    for (int j = tid; j < 257; j += 256)
      as_[h][j] = attn[((size_t)(b * 6 + h) * 64 + q) * 257 + j];
  __syncthreads();
  for (int idx = tid; idx < 384; idx += 256) {
    int h = idx >> 6, r = idx & 63;
    float s = 0.f;
#pragma unroll 4
    for (int j = 0; j < 257; ++j) s += as_[h][j] * bf2f(ms[j][r]);
    t[((size_t)(b * 6 + h) * 64 + q) * 64 + r] = s;
  }
}

// ---- out_pre[b,q,d] = sum_r t[b,h(d),q,r] * Wconv[q,d,r]; grid (q, d-chunk) ----
__global__ __launch_bounds__(256) void vproj_kernel(const float* __restrict__ t,
                                                    const float* __restrict__ Wconv,
                                                    short* __restrict__ op) {
  const int q = blockIdx.x, chunk = blockIdx.y;
  const int tid = threadIdx.x;
  __shared__ float ts[48][64];  // [b*6+h][r]
  for (int lin = tid; lin < 48 * 64; lin += 256) {
    int bh = lin >> 6, r = lin & 63;
    ts[bh][r] = t[((size_t)bh * 64 + q) * 64 + r];
  }
  __syncthreads();
  const int d = chunk * 256 + tid;
  const int h = d >> 7;  // wave-uniform
  const float4* w4 = (const float4*)(Wconv + ((size_t)q * 768 + d) * 64);
  float acc[8] = {0.f, 0.f, 0.f, 0.f, 0.f, 0.f, 0.f, 0.f};
#pragma unroll
  for (int r4 = 0; r4 < 16; ++r4) {
    float4 w = w4[r4];
#pragma unroll
    for (int bb = 0; bb < 8; ++bb) {
      acc[bb] += w.x * ts[bb * 6 + h][r4 * 4 + 0];
      acc[bb] += w.y * ts[bb * 6 + h][r4 * 4 + 1];
      acc[bb] += w.z * ts[bb * 6 + h][r4 * 4 + 2];
      acc[bb] += w.w * ts[bb * 6 + h][r4 * 4 + 3];
    }
  }
#pragma unroll
  for (int bb = 0; bb < 8; ++bb)
    op[((size_t)(bb * 64 + q)) * 768 + d] = f2bf(acc[bb]);
}

extern "C" void kernel_launch(void* const* d_in, const int* in_sizes, int n_in,
                              void* d_out, int out_size, void* d_ws, size_t ws_size,
                              hipStream_t stream) {
  const float* x = (const float*)d_in[0];       // (8,64,768)
  const float* ctx = (const float*)d_in[1];     // (8,257,768)
  const float* Wq = (const float*)d_in[2];      // (768,768)
  const float* Wk = (const float*)d_in[3];      // (768,768)
  const float* Wv1 = (const float*)d_in[4];     // (4096,768)
  const float* ln_g = (const float*)d_in[5];    // (4096)
  const float* ln_b = (const float*)d_in[6];    // (4096)
  const float* Wconv = (const float*)d_in[7];   // (64,768,64)
  const float* Wout = (const float*)d_in[8];    // (768,768)
  float* out = (float*)d_out;                   // (8,64,768) fp32
  (void)in_sizes; (void)n_in; (void)out_size; (void)ws_size;

  char* ws = (char*)d_ws;
  size_t off = 0;
  auto alloc = [&](size_t bytes) -> void* {
    void* p = (void*)(ws + off);
    off += (bytes + 255) & ~(size_t)255;
    return p;
  };
  short* x_bf    = (short*)alloc((size_t)393216 * 2);
  short* ctx_bf  = (short*)alloc((size_t)1579008 * 2);
  short* wq_bf   = (short*)alloc((size_t)589824 * 2);
  short* wk_bf   = (short*)alloc((size_t)589824 * 2);
  short* wv1_bf  = (short*)alloc((size_t)3145728 * 2);
  short* wout_bf = (short*)alloc((size_t)589824 * 2);
  short* q_bf    = (short*)alloc((size_t)393216 * 2);
  short* k_bf    = (short*)alloc((size_t)1579008 * 2);
  short* mid_bf  = (short*)alloc((size_t)8421376 * 2);
  float* attn    = (float*)alloc((size_t)789504 * 4);
  float* tbuf    = (float*)alloc((size_t)196608 * 4);
  short* op_bf   = (short*)alloc((size_t)393216 * 2);

  auto cvt = [&](const float* in, short* o, int n) {
    int n4 = n / 4;
    cvt_kernel<<<dim3((n4 + 255) / 256), dim3(256), 0, stream>>>(in, o, n4);
  };
  cvt(x, x_bf, 393216);
  cvt(ctx, ctx_bf, 1579008);
  cvt(Wq, wq_bf, 589824);
  cvt(Wk, wk_bf, 589824);
  cvt(Wv1, wv1_bf, 3145728);
  cvt(Wout, wout_bf, 589824);

  // q = x @ Wq^T   (512x768, K=768)
  gemm_nt<1><<<dim3(4, 6), dim3(256), 0, stream>>>(x_bf, wq_bf, q_bf, 512, 768, 768);
  // k = ctx @ Wk^T (2056x768, K=768)
  gemm_nt<1><<<dim3(17, 6), dim3(256), 0, stream>>>(ctx_bf, wk_bf, k_bf, 2056, 768, 768);
  // mid = ctx @ Wv1^T (2056x4096, K=768) -- dominant GEMM
  gemm_nt<1><<<dim3(17, 32), dim3(256), 0, stream>>>(ctx_bf, wv1_bf, mid_bf, 2056, 4096, 768);
  // LayerNorm rows of 4096, in-place
  ln_kernel<<<dim3(2056), dim3(256), 0, stream>>>(mid_bf, ln_g, ln_b);
  // QK^T + softmax
  attn_kernel<<<dim3(48), dim3(256), 0, stream>>>(q_bf, k_bf, attn);
  // t = attn . midq
  tk_kernel<<<dim3(512), dim3(256), 0, stream>>>(attn, mid_bf, tbuf);
  // out_pre = t . Wconv
  vproj_kernel<<<dim3(64, 3), dim3(256), 0, stream>>>(tbuf, Wconv, op_bf);
  // out = out_pre @ Wout^T, fp32 out
  gemm_nt<0><<<dim3(4, 6), dim3(256), 0, stream>>>(op_bf, wout_bf, out, 512, 768, 768);
}

// Round 2
// 188.302 us; speedup vs baseline: 1.5337x; 1.5337x over previous
//
#include <hip/hip_runtime.h>

#define DEV __device__ __forceinline__

typedef __attribute__((ext_vector_type(8))) short sv8;   // 8 x bf16 bits
typedef __attribute__((ext_vector_type(4))) short sv4;
typedef __attribute__((ext_vector_type(4))) float f32x4;

// ---- bf16 helpers (bit-level, round-to-nearest-even) ----
DEV short f2bf(float f) {
  unsigned u = __float_as_uint(f);
  unsigned r = (u + 0x7fffu + ((u >> 16) & 1u)) >> 16;
  return (short)r;
}
DEV float bf2f(short s) {
  return __uint_as_float(((unsigned)(unsigned short)s) << 16);
}

// ---- async global -> LDS, 16B per lane. LDS dest must be wave-uniform. ----
DEV void gload16(const void* g, void* l) {
  __builtin_amdgcn_global_load_lds((const __attribute__((address_space(1))) void*)g,
                                   (__attribute__((address_space(3))) void*)l, 16, 0, 0);
}

// ---- fused fp32 -> bf16 conversion for all 6 tensors, one launch ----
struct CvtArgs {
  const float* s0; const float* s1; const float* s2;
  const float* s3; const float* s4; const float* s5;
  short* d0; short* d1; short* d2; short* d3; short* d4; short* d5;
  int e0, e1, e2, e3, e4, e5;   // cumulative ends in float4 units
};
__global__ __launch_bounds__(256) void cvt_all(CvtArgs a) {
  int i = blockIdx.x * 256 + threadIdx.x;
  if (i >= a.e5) return;
  const float* s; short* d; int base;
  if      (i < a.e0) { s = a.s0; d = a.d0; base = 0; }
  else if (i < a.e1) { s = a.s1; d = a.d1; base = a.e0; }
  else if (i < a.e2) { s = a.s2; d = a.d2; base = a.e1; }
  else if (i < a.e3) { s = a.s3; d = a.d3; base = a.e2; }
  else if (i < a.e4) { s = a.s4; d = a.d4; base = a.e3; }
  else               { s = a.s5; d = a.d5; base = a.e4; }
  int j = i - base;
  float4 v = ((const float4*)s)[j];
  sv4 o = { f2bf(v.x), f2bf(v.y), f2bf(v.z), f2bf(v.w) };
  ((sv4*)d)[j] = o;
}

// ---- NT GEMM tile body: C[M,N] = A[M,K] * B[N,K]^T, 128x128 tile, BK=32 ----
// global_load_lds width-16 staging into linear [128][32] LDS (conflict-free read:
// 4 cols x 2 row parities x 16B = 8 lanes per 4-bank group = b128 minimum).
template <int OUT_BF16>
DEV void gemm_tile(const short* __restrict__ A, const short* __restrict__ B,
                   void* __restrict__ C, int M, int N, int K, int bm, int bn) {
  __shared__ __align__(16) short As[128 * 32];
  __shared__ __align__(16) short Bs[128 * 32];
  const int tid = threadIdx.x;
  const int wave = tid >> 6, lane = tid & 63;
  const int wr = wave >> 1, wc = wave & 1;
  const int row0 = bm * 128, col0 = bn * 128;
  const int rsel = lane & 15, koff = (lane >> 4) * 8;
  const int Am = M - 1, Bm = N - 1;
  const int lr = lane >> 2, c8 = (lane & 3) * 8;

  const f32x4 z = {0.f, 0.f, 0.f, 0.f};
  f32x4 acc[4][4];
#pragma unroll
  for (int m = 0; m < 4; ++m)
#pragma unroll
    for (int n = 0; n < 4; ++n) acc[m][n] = z;

  for (int k0 = 0; k0 < K; k0 += 32) {
#pragma unroll
    for (int s = 0; s < 2; ++s) {
      int chunk = s * 4 + wave;            // wave-uniform
      int rr = chunk * 16 + lr;
      int gr = row0 + rr; if (gr > Am) gr = Am;
      gload16(A + (size_t)gr * K + k0 + c8, As + chunk * 512);
      int gc = col0 + rr; if (gc > Bm) gc = Bm;
      gload16(B + (size_t)gc * K + k0 + c8, Bs + chunk * 512);
    }
    __syncthreads();   // compiler emits vmcnt(0) drain here
    sv8 a[4], b[4];
#pragma unroll
    for (int m = 0; m < 4; ++m) a[m] = *(const sv8*)(As + (wr * 64 + m * 16 + rsel) * 32 + koff);
#pragma unroll
    for (int n = 0; n < 4; ++n) b[n] = *(const sv8*)(Bs + (wc * 64 + n * 16 + rsel) * 32 + koff);
#pragma unroll
    for (int m = 0; m < 4; ++m)
#pragma unroll
      for (int n = 0; n < 4; ++n)
        acc[m][n] = __builtin_amdgcn_mfma_f32_16x16x32_bf16(a[m], b[n], acc[m][n], 0, 0, 0);
    __syncthreads();
  }

  const int cc = lane & 15, cr = (lane >> 4) * 4;
#pragma unroll
  for (int m = 0; m < 4; ++m)
#pragma unroll
    for (int n = 0; n < 4; ++n) {
      int c = col0 + wc * 64 + n * 16 + cc;
#pragma unroll
      for (int j = 0; j < 4; ++j) {
        int r = row0 + wr * 64 + m * 16 + cr + j;
        if (r < M && c < N) {
          float v = acc[m][n][j];
          if (OUT_BF16) ((short*)C)[(size_t)r * N + c] = f2bf(v);
          else          ((float*)C)[(size_t)r * N + c] = v;
        }
      }
    }
}

// ---- batched GEMM: q (24 blks) + k (102 blks) + mid (544 blks) in one launch ----
struct GSeg { const short* A; const short* B; short* C; int M; int nb; int blk0; };
__global__ __launch_bounds__(256) void gemm3(GSeg g0, GSeg g1, GSeg g2) {
  int bid = blockIdx.x;
  GSeg g;
  if (bid < g1.blk0) g = g0;
  else if (bid < g2.blk0) g = g1;
  else g = g2;
  int local = bid - g.blk0;
  int bm = local / g.nb, bn = local % g.nb;
  gemm_tile<1>(g.A, g.B, g.C, g.M, g.nb * 128, 768, bm, bn);
}

__global__ __launch_bounds__(256) void gemm_out_k(const short* __restrict__ A,
                                                  const short* __restrict__ B,
                                                  float* __restrict__ C) {
  gemm_tile<0>(A, B, C, 512, 768, 768, blockIdx.x, blockIdx.y);
}

// ---- merged LayerNorm + attention (QK^T + softmax) ----
DEV void ln_body(int row, short* __restrict__ mid, const float* __restrict__ g,
                 const float* __restrict__ bb, float* rs, float* rss) {
  short* p = mid + (size_t)row * 4096;
  const int tid = threadIdx.x;
  sv8 v0 = *(const sv8*)(p + tid * 16);
  sv8 v1 = *(const sv8*)(p + tid * 16 + 8);
  float x[16];
#pragma unroll
  for (int j = 0; j < 8; ++j) { x[j] = bf2f(v0[j]); x[8 + j] = bf2f(v1[j]); }
  float s = 0.f, ss = 0.f;
#pragma unroll
  for (int j = 0; j < 16; ++j) { s += x[j]; ss += x[j] * x[j]; }
#pragma unroll
  for (int off = 32; off; off >>= 1) { s += __shfl_xor(s, off); ss += __shfl_xor(ss, off); }
  if ((tid & 63) == 0) { rs[tid >> 6] = s; rss[tid >> 6] = ss; }
  __syncthreads();
  float S = rs[0] + rs[1] + rs[2] + rs[3];
  float SS = rss[0] + rss[1] + rss[2] + rss[3];
  const float inv_n = 1.0f / 4096.0f;
  float mu = S * inv_n;
  float var = SS * inv_n - mu * mu;
  float rstd = rsqrtf(var + 1e-5f);
  const float4* g4 = (const float4*)(g + tid * 16);
  const float4* b4 = (const float4*)(bb + tid * 16);
  float y[16];
#pragma unroll
  for (int i = 0; i < 4; ++i) {
    float4 gg = g4[i], bv = b4[i];
    y[i * 4 + 0] = (x[i * 4 + 0] - mu) * rstd * gg.x + bv.x;
    y[i * 4 + 1] = (x[i * 4 + 1] - mu) * rstd * gg.y + bv.y;
    y[i * 4 + 2] = (x[i * 4 + 2] - mu) * rstd * gg.z + bv.z;
    y[i * 4 + 3] = (x[i * 4 + 3] - mu) * rstd * gg.w + bv.w;
  }
  sv8 o0, o1;
#pragma unroll
  for (int j = 0; j < 8; ++j) { o0[j] = f2bf(y[j]); o1[j] = f2bf(y[8 + j]); }
  *(sv8*)(p + tid * 16) = o0;
  *(sv8*)(p + tid * 16 + 8) = o1;
}

DEV void attn_body(int bh, const short* __restrict__ qb, const short* __restrict__ kb,
                   float* __restrict__ attn, float (*wred)[64]) {
  const int b = bh / 6, h = bh % 6;
  const int tid = threadIdx.x, wave = tid >> 6, lane = tid & 63;
  const int rsel = lane & 15, koff = (lane >> 4) * 8;
  const int rhi = (lane >> 4) * 4;

  const f32x4 z = {0.f, 0.f, 0.f, 0.f};
  f32x4 acc[4][5];
#pragma unroll
  for (int m = 0; m < 4; ++m)
#pragma unroll
    for (int i = 0; i < 5; ++i) acc[m][i] = z;

#pragma unroll
  for (int k0 = 0; k0 < 128; k0 += 32) {
    sv8 a[4];
#pragma unroll
    for (int m = 0; m < 4; ++m)
      a[m] = *(const sv8*)(qb + (size_t)(b * 64 + m * 16 + rsel) * 768 + h * 128 + k0 + koff);
#pragma unroll
    for (int i = 0; i < 5; ++i) {
      int nf = wave + i * 4;
      if (nf > 16) continue;  // wave-uniform
      int j = nf * 16 + rsel; if (j > 256) j = 256;
      sv8 bf = *(const sv8*)(kb + (size_t)(b * 257 + j) * 768 + h * 128 + k0 + koff);
#pragma unroll
      for (int m = 0; m < 4; ++m)
        acc[m][i] = __builtin_amdgcn_mfma_f32_16x16x32_bf16(a[m], bf, acc[m][i], 0, 0, 0);
    }
  }
  // scale + mask invalid cols in-register
  const float S2 = 0.08838834764831845f;  // 1/sqrt(128)
#pragma unroll
  for (int m = 0; m < 4; ++m)
#pragma unroll
    for (int i = 0; i < 5; ++i) {
      int col = (wave + i * 4) * 16 + rsel;
      bool valid = col < 257;
#pragma unroll
      for (int j = 0; j < 4; ++j)
        acc[m][i][j] = valid ? acc[m][i][j] * S2 : -1e30f;
    }
  // per-row max: in-lane over i, butterfly over 16-lane col group, cross-wave via LDS
  float mx[4][4];
#pragma unroll
  for (int m = 0; m < 4; ++m)
#pragma unroll
    for (int j = 0; j < 4; ++j) {
      float pm = acc[m][0][j];
#pragma unroll
      for (int i = 1; i < 5; ++i) pm = fmaxf(pm, acc[m][i][j]);
      pm = fmaxf(pm, __shfl_xor(pm, 1));
      pm = fmaxf(pm, __shfl_xor(pm, 2));
      pm = fmaxf(pm, __shfl_xor(pm, 4));
      pm = fmaxf(pm, __shfl_xor(pm, 8));
      mx[m][j] = pm;
      if (rsel == 0) wred[wave][m * 16 + rhi + j] = pm;
    }
  __syncthreads();
#pragma unroll
  for (int m = 0; m < 4; ++m)
#pragma unroll
    for (int j = 0; j < 4; ++j) {
      int row = m * 16 + rhi + j;
      mx[m][j] = fmaxf(fmaxf(wred[0][row], wred[1][row]), fmaxf(wred[2][row], wred[3][row]));
    }
  __syncthreads();  // wred reuse
  // exp + per-row sum
  float inv[4][4];
#pragma unroll
  for (int m = 0; m < 4; ++m)
#pragma unroll
    for (int j = 0; j < 4; ++j) {
      float ps = 0.f;
#pragma unroll
      for (int i = 0; i < 5; ++i) {
        float e = __expf(acc[m][i][j] - mx[m][j]);
        acc[m][i][j] = e;
        ps += e;
      }
      ps += __shfl_xor(ps, 1);
      ps += __shfl_xor(ps, 2);
      ps += __shfl_xor(ps, 4);
      ps += __shfl_xor(ps, 8);
      if (rsel == 0) wred[wave][m * 16 + rhi + j] = ps;
    }
  __syncthreads();
  float* base = attn + (size_t)bh * 64 * 257;
#pragma unroll
  for (int m = 0; m < 4; ++m)
#pragma unroll
    for (int j = 0; j < 4; ++j) {
      int row = m * 16 + rhi + j;
      float tot = wred[0][row] + wred[1][row] + wred[2][row] + wred[3][row];
      inv[m][j] = 1.f / tot;
    }
#pragma unroll
  for (int m = 0; m < 4; ++m)
#pragma unroll
    for (int i = 0; i < 5; ++i) {
      int nf = wave + i * 4;
      if (nf > 16) continue;
      int col = nf * 16 + rsel;
      if (col < 257) {
#pragma unroll
        for (int j = 0; j < 4; ++j)
          base[(size_t)(m * 16 + rhi + j) * 257 + col] = acc[m][i][j] * inv[m][j];
      }
    }
}

__global__ __launch_bounds__(256) void ln_attn(short* __restrict__ mid,
                                               const float* __restrict__ g,
                                               const float* __restrict__ bb,
                                               const short* __restrict__ qb,
                                               const short* __restrict__ kb,
                                               float* __restrict__ attn) {
  __shared__ float wred[4][64];
  __shared__ float rs[4], rss[4];
  if (blockIdx.x < 48) attn_body(blockIdx.x, qb, kb, attn, wred);
  else                 ln_body(blockIdx.x - 48, mid, g, bb, rs, rss);
}

// ---- t[b,h,q,r] = sum_j attn[b,h,q,j] * mid_ln[b,j,q*64+r]; one block per (b,q) ----
__global__ __launch_bounds__(256) void tk_kernel(const float* __restrict__ attn,
                                                 const short* __restrict__ mid,
                                                 float* __restrict__ t) {
  const int bq = blockIdx.x;
  const int b = bq >> 6, q = bq & 63;
  const int tid = threadIdx.x;
  __shared__ short ms[257][64];
  __shared__ float as_[6][257];
  for (int lin = tid; lin < 257 * 8; lin += 256) {
    int j = lin >> 3, seg = (lin & 7) * 8;
    *(sv8*)(&ms[j][seg]) = *(const sv8*)(mid + (size_t)(b * 257 + j) * 4096 + q * 64 + seg);
  }
#pragma unroll
  for (int h = 0; h < 6; ++h)
    for (int j = tid; j < 257; j += 256)
      as_[h][j] = attn[((size_t)(b * 6 + h) * 64 + q) * 257 + j];
  __syncthreads();
  for (int idx = tid; idx < 384; idx += 256) {
    int h = idx >> 6, r = idx & 63;
    float s = 0.f;
#pragma unroll 4
    for (int j = 0; j < 257; ++j) s += as_[h][j] * bf2f(ms[j][r]);
    t[((size_t)(b * 6 + h) * 64 + q) * 64 + r] = s;
  }
}

// ---- out_pre[b,q,d] = sum_r t[b,h(d),q,r] * Wconv[q,d,r]; grid (q, d-chunk) ----
__global__ __launch_bounds__(256) void vproj_kernel(const float* __restrict__ t,
                                                    const float* __restrict__ Wconv,
                                                    short* __restrict__ op) {
  const int q = blockIdx.x, chunk = blockIdx.y;
  const int tid = threadIdx.x;
  __shared__ float ts[48][64];
  for (int lin = tid; lin < 48 * 64; lin += 256) {
    int bh = lin >> 6, r = lin & 63;
    ts[bh][r] = t[((size_t)bh * 64 + q) * 64 + r];
  }
  __syncthreads();
  const int d = chunk * 256 + tid;
  const int h = d >> 7;  // wave-uniform
  const float4* w4 = (const float4*)(Wconv + ((size_t)q * 768 + d) * 64);
  float acc[8] = {0.f, 0.f, 0.f, 0.f, 0.f, 0.f, 0.f, 0.f};
#pragma unroll
  for (int r4 = 0; r4 < 16; ++r4) {
    float4 w = w4[r4];
#pragma unroll
    for (int bb = 0; bb < 8; ++bb) {
      acc[bb] += w.x * ts[bb * 6 + h][r4 * 4 + 0];
      acc[bb] += w.y * ts[bb * 6 + h][r4 * 4 + 1];
      acc[bb] += w.z * ts[bb * 6 + h][r4 * 4 + 2];
      acc[bb] += w.w * ts[bb * 6 + h][r4 * 4 + 3];
    }
  }
#pragma unroll
  for (int bb = 0; bb < 8; ++bb)
    op[((size_t)(bb * 64 + q)) * 768 + d] = f2bf(acc[bb]);
}

extern "C" void kernel_launch(void* const* d_in, const int* in_sizes, int n_in,
                              void* d_out, int out_size, void* d_ws, size_t ws_size,
                              hipStream_t stream) {
  const float* x = (const float*)d_in[0];
  const float* ctx = (const float*)d_in[1];
  const float* Wq = (const float*)d_in[2];
  const float* Wk = (const float*)d_in[3];
  const float* Wv1 = (const float*)d_in[4];
  const float* ln_g = (const float*)d_in[5];
  const float* ln_b = (const float*)d_in[6];
  const float* Wconv = (const float*)d_in[7];
  const float* Wout = (const float*)d_in[8];
  float* out = (float*)d_out;
  (void)in_sizes; (void)n_in; (void)out_size; (void)ws_size;

  char* ws = (char*)d_ws;
  size_t off = 0;
  auto alloc = [&](size_t bytes) -> void* {
    void* p = (void*)(ws + off);
    off += (bytes + 255) & ~(size_t)255;
    return p;
  };
  short* x_bf    = (short*)alloc((size_t)393216 * 2);
  short* ctx_bf  = (short*)alloc((size_t)1579008 * 2);
  short* wq_bf   = (short*)alloc((size_t)589824 * 2);
  short* wk_bf   = (short*)alloc((size_t)589824 * 2);
  short* wv1_bf  = (short*)alloc((size_t)3145728 * 2);
  short* wout_bf = (short*)alloc((size_t)589824 * 2);
  short* q_bf    = (short*)alloc((size_t)393216 * 2);
  short* k_bf    = (short*)alloc((size_t)1579008 * 2);
  short* mid_bf  = (short*)alloc((size_t)8421376 * 2);
  float* attn    = (float*)alloc((size_t)789504 * 4);
  float* tbuf    = (float*)alloc((size_t)196608 * 4);
  short* op_bf   = (short*)alloc((size_t)393216 * 2);

  // 1. convert everything fp32 -> bf16 in one launch
  CvtArgs ca;
  ca.s0 = x;   ca.d0 = x_bf;    int n0 = 393216 / 4;
  ca.s1 = ctx; ca.d1 = ctx_bf;  int n1 = 1579008 / 4;
  ca.s2 = Wq;  ca.d2 = wq_bf;   int n2 = 589824 / 4;
  ca.s3 = Wk;  ca.d3 = wk_bf;   int n3 = 589824 / 4;
  ca.s4 = Wv1; ca.d4 = wv1_bf;  int n4 = 3145728 / 4;
  ca.s5 = Wout; ca.d5 = wout_bf; int n5 = 589824 / 4;
  ca.e0 = n0; ca.e1 = ca.e0 + n1; ca.e2 = ca.e1 + n2;
  ca.e3 = ca.e2 + n3; ca.e4 = ca.e3 + n4; ca.e5 = ca.e4 + n5;
  cvt_all<<<dim3((ca.e5 + 255) / 256), dim3(256), 0, stream>>>(ca);

  // 2. q + k + mid GEMMs in one launch (24 + 102 + 544 = 670 blocks)
  GSeg s_q   = { x_bf,   wq_bf,  q_bf,   512,  6, 0 };
  GSeg s_k   = { ctx_bf, wk_bf,  k_bf,   2056, 6, 24 };
  GSeg s_mid = { ctx_bf, wv1_bf, mid_bf, 2056, 32, 126 };
  gemm3<<<dim3(670), dim3(256), 0, stream>>>(s_q, s_k, s_mid);

  // 3. LayerNorm (2056 blocks) + attention (48 blocks, scheduled first)
  ln_attn<<<dim3(2104), dim3(256), 0, stream>>>(mid_bf, ln_g, ln_b, q_bf, k_bf, attn);

  // 4. t = attn . midq
  tk_kernel<<<dim3(512), dim3(256), 0, stream>>>(attn, mid_bf, tbuf);

  // 5. out_pre = t . Wconv
  vproj_kernel<<<dim3(64, 3), dim3(256), 0, stream>>>(tbuf, Wconv, op_bf);

  // 6. out = out_pre @ Wout^T (fp32 out)
  gemm_out_k<<<dim3(4, 6), dim3(256), 0, stream>>>(op_bf, wout_bf, out);
}

// Round 5
// 183.511 us; speedup vs baseline: 1.5737x; 1.0261x over previous
//
#include <hip/hip_runtime.h>

#define DEV __device__ __forceinline__

typedef __attribute__((ext_vector_type(8))) short sv8;   // 8 x bf16 bits
typedef __attribute__((ext_vector_type(4))) short sv4;
typedef __attribute__((ext_vector_type(4))) float f32x4;

// ---- bf16 helpers (bit-level, round-to-nearest-even) ----
DEV short f2bf(float f) {
  unsigned u = __float_as_uint(f);
  unsigned r = (u + 0x7fffu + ((u >> 16) & 1u)) >> 16;
  return (short)r;
}
DEV float bf2f(short s) {
  return __uint_as_float(((unsigned)(unsigned short)s) << 16);
}

// ---- async global -> LDS, 16B per lane. LDS dest = wave-uniform base + lane*16 ----
DEV void gload16(const void* g, void* l) {
  __builtin_amdgcn_global_load_lds((const __attribute__((address_space(1))) void*)g,
                                   (__attribute__((address_space(3))) void*)l, 16, 0, 0);
}

// ---- zero-fill d_out (needed for split-K atomic accumulation) ----
__global__ __launch_bounds__(256) void fill_zero(float* __restrict__ p, int n4) {
  int i = blockIdx.x * 256 + threadIdx.x;
  if (i < n4) ((float4*)p)[i] = make_float4(0.f, 0.f, 0.f, 0.f);
}

// ---- fused fp32 -> bf16 conversion for all 6 tensors, one launch ----
struct CvtArgs {
  const float* s0; const float* s1; const float* s2;
  const float* s3; const float* s4; const float* s5;
  short* d0; short* d1; short* d2; short* d3; short* d4; short* d5;
  int e0, e1, e2, e3, e4, e5;   // cumulative ends in float4 units
};
__global__ __launch_bounds__(256) void cvt_all(CvtArgs a) {
  int i = blockIdx.x * 256 + threadIdx.x;
  if (i >= a.e5) return;
  const float* s; short* d; int base;
  if      (i < a.e0) { s = a.s0; d = a.d0; base = 0; }
  else if (i < a.e1) { s = a.s1; d = a.d1; base = a.e0; }
  else if (i < a.e2) { s = a.s2; d = a.d2; base = a.e1; }
  else if (i < a.e3) { s = a.s3; d = a.d3; base = a.e2; }
  else if (i < a.e4) { s = a.s4; d = a.d4; base = a.e3; }
  else               { s = a.s5; d = a.d5; base = a.e4; }
  int j = i - base;
  float4 v = ((const float4*)s)[j];
  sv4 o = { f2bf(v.x), f2bf(v.y), f2bf(v.z), f2bf(v.w) };
  ((sv4*)d)[j] = o;
}

// ---- NT GEMM tile: C[M,N] = A[M,K]*B[N,K]^T, 128x128 tile, BK=32, 2-phase dbuf ----
// LDS layout: linear [128][32] bf16 per buffer with 16B-slot XOR swizzle.
// Logical (row, slot s) lives at LDS slot s^(row&3); gload_lds writes linearly so the
// per-lane GLOBAL source is inverse-swizzled (same involution), reads apply the XOR.
// MODE: 0 = f32 store, 1 = bf16 store, 2 = f32 atomicAdd (split-K).
template <int MODE, int SPLITK>
DEV void gemm_tile(const short* __restrict__ A, const short* __restrict__ B,
                   void* __restrict__ C, int M, int N, int K,
                   int bm, int bn, int ks) {
  __shared__ __align__(16) short As[2][4096];
  __shared__ __align__(16) short Bs[2][4096];
  const int tid = threadIdx.x;
  const int wave = tid >> 6, lane = tid & 63;
  const int wr = wave >> 1, wc = wave & 1;
  const int row0 = bm * 128, col0 = bn * 128;
  const int rsel = lane & 15;
  const int Am = M - 1, Bm = N - 1;
  const int lr = lane >> 2;
  const int c8 = ((lane & 3) ^ ((lane >> 2) & 3)) * 8;  // inverse-swizzled source slot
  const int Ksl = K / SPLITK;
  const int kbase = ks * Ksl;
  const int nt = Ksl / 32;

  const f32x4 z = {0.f, 0.f, 0.f, 0.f};
  f32x4 acc[4][4];
#pragma unroll
  for (int m = 0; m < 4; ++m)
#pragma unroll
    for (int n = 0; n < 4; ++n) acc[m][n] = z;

  auto stage = [&](int t, int buf) {
    int k0 = kbase + t * 32;
#pragma unroll
    for (int s = 0; s < 2; ++s) {
      int chunk = s * 4 + wave;            // wave-uniform LDS chunk
      int rr = chunk * 16 + lr;
      int gr = row0 + rr; if (gr > Am) gr = Am;
      gload16(A + (size_t)gr * K + k0 + c8, &As[buf][chunk * 512]);
      int gc = col0 + rr; if (gc > Bm) gc = Bm;
      gload16(B + (size_t)gc * K + k0 + c8, &Bs[buf][chunk * 512]);
    }
  };

  stage(0, 0);
  __syncthreads();                         // buf0 landed (vmcnt(0) in barrier)
  const int ko = (((lane >> 4) ^ (rsel & 3)) * 8);  // swizzled read slot (row&3==rsel&3)

  for (int t = 0; t < nt; ++t) {
    int cur = t & 1;
    if (t + 1 < nt) stage(t + 1, cur ^ 1); // prefetch overlaps this tile's compute
    sv8 a[4], b[4];
#pragma unroll
    for (int m = 0; m < 4; ++m)
      a[m] = *(const sv8*)(&As[cur][(wr * 64 + m * 16 + rsel) * 32 + ko]);
#pragma unroll
    for (int n = 0; n < 4; ++n)
      b[n] = *(const sv8*)(&Bs[cur][(wc * 64 + n * 16 + rsel) * 32 + ko]);
#pragma unroll
    for (int m = 0; m < 4; ++m)
#pragma unroll
      for (int n = 0; n < 4; ++n)
        acc[m][n] = __builtin_amdgcn_mfma_f32_16x16x32_bf16(a[m], b[n], acc[m][n], 0, 0, 0);
    __syncthreads();                       // drain prefetch + publish read-completion
  }

  const int cc = lane & 15, cr = (lane >> 4) * 4;
#pragma unroll
  for (int m = 0; m < 4; ++m)
#pragma unroll
    for (int n = 0; n < 4; ++n) {
      int c = col0 + wc * 64 + n * 16 + cc;
#pragma unroll
      for (int j = 0; j < 4; ++j) {
        int r = row0 + wr * 64 + m * 16 + cr + j;
        if (r < M && c < N) {
          float v = acc[m][n][j];
          if (MODE == 1)      ((short*)C)[(size_t)r * N + c] = f2bf(v);
          else if (MODE == 0) ((float*)C)[(size_t)r * N + c] = v;
          else                atomicAdd(&((float*)C)[(size_t)r * N + c], v);
        }
      }
    }
}

// ---- batched GEMM: q (24 blks) + k (102 blks) + mid (544 blks) in one launch ----
struct GSeg { const short* A; const short* B; short* C; int M; int nb; int blk0; };
__global__ __launch_bounds__(256) void gemm3(GSeg g0, GSeg g1, GSeg g2) {
  int bid = blockIdx.x;
  GSeg g;
  if (bid < g1.blk0) g = g0;
  else if (bid < g2.blk0) g = g1;
  else g = g2;
  int local = bid - g.blk0;
  int bm = local / g.nb, bn = local % g.nb;
  gemm_tile<1, 1>(g.A, g.B, g.C, g.M, g.nb * 128, 768, bm, bn, 0);
}

// ---- out GEMM: split-K=4, fp32 atomic accumulate into zeroed d_out ----
__global__ __launch_bounds__(256) void gemm_out_k(const short* __restrict__ A,
                                                  const short* __restrict__ B,
                                                  float* __restrict__ C) {
  gemm_tile<2, 4>(A, B, C, 512, 768, 768, blockIdx.x, blockIdx.y, blockIdx.z);
}

// ---- merged LayerNorm + attention (QK^T + softmax) ----
DEV void ln_body(int row, short* __restrict__ mid, const float* __restrict__ g,
                 const float* __restrict__ bb, float* rs, float* rss) {
  short* p = mid + (size_t)row * 4096;
  const int tid = threadIdx.x;
  sv8 v0 = *(const sv8*)(p + tid * 16);
  sv8 v1 = *(const sv8*)(p + tid * 16 + 8);
  float x[16];
#pragma unroll
  for (int j = 0; j < 8; ++j) { x[j] = bf2f(v0[j]); x[8 + j] = bf2f(v1[j]); }
  float s = 0.f, ss = 0.f;
#pragma unroll
  for (int j = 0; j < 16; ++j) { s += x[j]; ss += x[j] * x[j]; }
#pragma unroll
  for (int off = 32; off; off >>= 1) { s += __shfl_xor(s, off); ss += __shfl_xor(ss, off); }
  if ((tid & 63) == 0) { rs[tid >> 6] = s; rss[tid >> 6] = ss; }
  __syncthreads();
  float S = rs[0] + rs[1] + rs[2] + rs[3];
  float SS = rss[0] + rss[1] + rss[2] + rss[3];
  const float inv_n = 1.0f / 4096.0f;
  float mu = S * inv_n;
  float var = SS * inv_n - mu * mu;
  float rstd = rsqrtf(var + 1e-5f);
  const float4* g4 = (const float4*)(g + tid * 16);
  const float4* b4 = (const float4*)(bb + tid * 16);
  float y[16];
#pragma unroll
  for (int i = 0; i < 4; ++i) {
    float4 gg = g4[i], bv = b4[i];
    y[i * 4 + 0] = (x[i * 4 + 0] - mu) * rstd * gg.x + bv.x;
    y[i * 4 + 1] = (x[i * 4 + 1] - mu) * rstd * gg.y + bv.y;
    y[i * 4 + 2] = (x[i * 4 + 2] - mu) * rstd * gg.z + bv.z;
    y[i * 4 + 3] = (x[i * 4 + 3] - mu) * rstd * gg.w + bv.w;
  }
  sv8 o0, o1;
#pragma unroll
  for (int j = 0; j < 8; ++j) { o0[j] = f2bf(y[j]); o1[j] = f2bf(y[8 + j]); }
  *(sv8*)(p + tid * 16) = o0;
  *(sv8*)(p + tid * 16 + 8) = o1;
}

DEV void attn_body(int bh, const short* __restrict__ qb, const short* __restrict__ kb,
                   float* __restrict__ attn, float (*wred)[64]) {
  const int b = bh / 6, h = bh % 6;
  const int tid = threadIdx.x, wave = tid >> 6, lane = tid & 63;
  const int rsel = lane & 15, koff = (lane >> 4) * 8;
  const int rhi = (lane >> 4) * 4;

  const f32x4 z = {0.f, 0.f, 0.f, 0.f};
  f32x4 acc[4][5];
#pragma unroll
  for (int m = 0; m < 4; ++m)
#pragma unroll
    for (int i = 0; i < 5; ++i) acc[m][i] = z;

#pragma unroll
  for (int k0 = 0; k0 < 128; k0 += 32) {
    sv8 a[4];
#pragma unroll
    for (int m = 0; m < 4; ++m)
      a[m] = *(const sv8*)(qb + (size_t)(b * 64 + m * 16 + rsel) * 768 + h * 128 + k0 + koff);
#pragma unroll
    for (int i = 0; i < 5; ++i) {
      int nf = wave + i * 4;
      if (nf > 16) continue;  // wave-uniform
      int j = nf * 16 + rsel; if (j > 256) j = 256;
      sv8 bf = *(const sv8*)(kb + (size_t)(b * 257 + j) * 768 + h * 128 + k0 + koff);
#pragma unroll
      for (int m = 0; m < 4; ++m)
        acc[m][i] = __builtin_amdgcn_mfma_f32_16x16x32_bf16(a[m], bf, acc[m][i], 0, 0, 0);
    }
  }
  const float S2 = 0.08838834764831845f;  // 1/sqrt(128)
#pragma unroll
  for (int m = 0; m < 4; ++m)
#pragma unroll
    for (int i = 0; i < 5; ++i) {
      int col = (wave + i * 4) * 16 + rsel;
      bool valid = col < 257;
#pragma unroll
      for (int j = 0; j < 4; ++j)
        acc[m][i][j] = valid ? acc[m][i][j] * S2 : -1e30f;
    }
  float mx[4][4];
#pragma unroll
  for (int m = 0; m < 4; ++m)
#pragma unroll
    for (int j = 0; j < 4; ++j) {
      float pm = acc[m][0][j];
#pragma unroll
      for (int i = 1; i < 5; ++i) pm = fmaxf(pm, acc[m][i][j]);
      pm = fmaxf(pm, __shfl_xor(pm, 1));
      pm = fmaxf(pm, __shfl_xor(pm, 2));
      pm = fmaxf(pm, __shfl_xor(pm, 4));
      pm = fmaxf(pm, __shfl_xor(pm, 8));
      mx[m][j] = pm;
      if (rsel == 0) wred[wave][m * 16 + rhi + j] = pm;
    }
  __syncthreads();
#pragma unroll
  for (int m = 0; m < 4; ++m)
#pragma unroll
    for (int j = 0; j < 4; ++j) {
      int row = m * 16 + rhi + j;
      mx[m][j] = fmaxf(fmaxf(wred[0][row], wred[1][row]), fmaxf(wred[2][row], wred[3][row]));
    }
  __syncthreads();
  float inv[4][4];
#pragma unroll
  for (int m = 0; m < 4; ++m)
#pragma unroll
    for (int j = 0; j < 4; ++j) {
      float ps = 0.f;
#pragma unroll
      for (int i = 0; i < 5; ++i) {
        float e = __expf(acc[m][i][j] - mx[m][j]);
        acc[m][i][j] = e;
        ps += e;
      }
      ps += __shfl_xor(ps, 1);
      ps += __shfl_xor(ps, 2);
      ps += __shfl_xor(ps, 4);
      ps += __shfl_xor(ps, 8);
      if (rsel == 0) wred[wave][m * 16 + rhi + j] = ps;
    }
  __syncthreads();
  float* base = attn + (size_t)bh * 64 * 257;
#pragma unroll
  for (int m = 0; m < 4; ++m)
#pragma unroll
    for (int j = 0; j < 4; ++j) {
      int row = m * 16 + rhi + j;
      float tot = wred[0][row] + wred[1][row] + wred[2][row] + wred[3][row];
      inv[m][j] = 1.f / tot;
    }
#pragma unroll
  for (int m = 0; m < 4; ++m)
#pragma unroll
    for (int i = 0; i < 5; ++i) {
      int nf = wave + i * 4;
      if (nf > 16) continue;
      int col = nf * 16 + rsel;
      if (col < 257) {
#pragma unroll
        for (int j = 0; j < 4; ++j)
          base[(size_t)(m * 16 + rhi + j) * 257 + col] = acc[m][i][j] * inv[m][j];
      }
    }
}

__global__ __launch_bounds__(256) void ln_attn(short* __restrict__ mid,
                                               const float* __restrict__ g,
                                               const float* __restrict__ bb,
                                               const short* __restrict__ qb,
                                               const short* __restrict__ kb,
                                               float* __restrict__ attn) {
  __shared__ float wred[4][64];
  __shared__ float rs[4], rss[4];
  if (blockIdx.x < 48) attn_body(blockIdx.x, qb, kb, attn, wred);
  else                 ln_body(blockIdx.x - 48, mid, g, bb, rs, rss);
}

// ---- t[b,h,q,r] = sum_j attn[b,h,q,j] * mid_ln[b,j,q*64+r]; one block per (b,q) ----
__global__ __launch_bounds__(256) void tk_kernel(const float* __restrict__ attn,
                                                 const short* __restrict__ mid,
                                                 float* __restrict__ t) {
  const int bq = blockIdx.x;
  const int b = bq >> 6, q = bq & 63;
  const int tid = threadIdx.x;
  __shared__ short ms[257][64];
  __shared__ float as_[6][257];
  for (int lin = tid; lin < 257 * 8; lin += 256) {
    int j = lin >> 3, seg = (lin & 7) * 8;
    *(sv8*)(&ms[j][seg]) = *(const sv8*)(mid + (size_t)(b * 257 + j) * 4096 + q * 64 + seg);
  }
#pragma unroll
  for (int h = 0; h < 6; ++h)
    for (int j = tid; j < 257; j += 256)
      as_[h][j] = attn[((size_t)(b * 6 + h) * 64 + q) * 257 + j];
  __syncthreads();
  for (int idx = tid; idx < 384; idx += 256) {
    int h = idx >> 6, r = idx & 63;
    float s = 0.f;
#pragma unroll 4
    for (int j = 0; j < 257; ++j) s += as_[h][j] * bf2f(ms[j][r]);
    t[((size_t)(b * 6 + h) * 64 + q) * 64 + r] = s;
  }
}

// ---- out_pre[b,q,d] = sum_r t[b,h(d),q,r] * Wconv[q,d,r]; grid (q, d-chunk) ----
__global__ __launch_bounds__(256) void vproj_kernel(const float* __restrict__ t,
                                                    const float* __restrict__ Wconv,
                                                    short* __restrict__ op) {
  const int q = blockIdx.x, chunk = blockIdx.y;
  const int tid = threadIdx.x;
  __shared__ float ts[48][64];
  for (int lin = tid; lin < 48 * 64; lin += 256) {
    int bh = lin >> 6, r = lin & 63;
    ts[bh][r] = t[((size_t)bh * 64 + q) * 64 + r];
  }
  __syncthreads();
  const int d = chunk * 256 + tid;
  const int h = d >> 7;  // wave-uniform
  const float4* w4 = (const float4*)(Wconv + ((size_t)q * 768 + d) * 64);
  float acc[8] = {0.f, 0.f, 0.f, 0.f, 0.f, 0.f, 0.f, 0.f};
#pragma unroll
  for (int r4 = 0; r4 < 16; ++r4) {
    float4 w = w4[r4];
#pragma unroll
    for (int bb = 0; bb < 8; ++bb) {
      acc[bb] += w.x * ts[bb * 6 + h][r4 * 4 + 0];
      acc[bb] += w.y * ts[bb * 6 + h][r4 * 4 + 1];
      acc[bb] += w.z * ts[bb * 6 + h][r4 * 4 + 2];
      acc[bb] += w.w * ts[bb * 6 + h][r4 * 4 + 3];
    }
  }
#pragma unroll
  for (int bb = 0; bb < 8; ++bb)
    op[((size_t)(bb * 64 + q)) * 768 + d] = f2bf(acc[bb]);
}

extern "C" void kernel_launch(void* const* d_in, const int* in_sizes, int n_in,
                              void* d_out, int out_size, void* d_ws, size_t ws_size,
                              hipStream_t stream) {
  const float* x = (const float*)d_in[0];
  const float* ctx = (const float*)d_in[1];
  const float* Wq = (const float*)d_in[2];
  const float* Wk = (const float*)d_in[3];
  const float* Wv1 = (const float*)d_in[4];
  const float* ln_g = (const float*)d_in[5];
  const float* ln_b = (const float*)d_in[6];
  const float* Wconv = (const float*)d_in[7];
  const float* Wout = (const float*)d_in[8];
  float* out = (float*)d_out;
  (void)in_sizes; (void)n_in; (void)out_size; (void)ws_size;

  char* ws = (char*)d_ws;
  size_t off = 0;
  auto alloc = [&](size_t bytes) -> void* {
    void* p = (void*)(ws + off);
    off += (bytes + 255) & ~(size_t)255;
    return p;
  };
  short* x_bf    = (short*)alloc((size_t)393216 * 2);
  short* ctx_bf  = (short*)alloc((size_t)1579008 * 2);
  short* wq_bf   = (short*)alloc((size_t)589824 * 2);
  short* wk_bf   = (short*)alloc((size_t)589824 * 2);
  short* wv1_bf  = (short*)alloc((size_t)3145728 * 2);
  short* wout_bf = (short*)alloc((size_t)589824 * 2);
  short* q_bf    = (short*)alloc((size_t)393216 * 2);
  short* k_bf    = (short*)alloc((size_t)1579008 * 2);
  short* mid_bf  = (short*)alloc((size_t)8421376 * 2);
  float* attn    = (float*)alloc((size_t)789504 * 4);
  float* tbuf    = (float*)alloc((size_t)196608 * 4);
  short* op_bf   = (short*)alloc((size_t)393216 * 2);

  // 0. zero d_out (atomic split-K target); runs ahead of everything that matters
  fill_zero<<<dim3(384), dim3(256), 0, stream>>>(out, 393216 / 4);

  // 1. convert everything fp32 -> bf16 in one launch
  CvtArgs ca;
  ca.s0 = x;   ca.d0 = x_bf;    int n0 = 393216 / 4;
  ca.s1 = ctx; ca.d1 = ctx_bf;  int n1 = 1579008 / 4;
  ca.s2 = Wq;  ca.d2 = wq_bf;   int n2 = 589824 / 4;
  ca.s3 = Wk;  ca.d3 = wk_bf;   int n3 = 589824 / 4;
  ca.s4 = Wv1; ca.d4 = wv1_bf;  int n4 = 3145728 / 4;
  ca.s5 = Wout; ca.d5 = wout_bf; int n5 = 589824 / 4;
  ca.e0 = n0; ca.e1 = ca.e0 + n1; ca.e2 = ca.e1 + n2;
  ca.e3 = ca.e2 + n3; ca.e4 = ca.e3 + n4; ca.e5 = ca.e4 + n5;
  cvt_all<<<dim3((ca.e5 + 255) / 256), dim3(256), 0, stream>>>(ca);

  // 2. q + k + mid GEMMs in one launch (24 + 102 + 544 = 670 blocks)
  GSeg s_q   = { x_bf,   wq_bf,  q_bf,   512,  6, 0 };
  GSeg s_k   = { ctx_bf, wk_bf,  k_bf,   2056, 6, 24 };
  GSeg s_mid = { ctx_bf, wv1_bf, mid_bf, 2056, 32, 126 };
  gemm3<<<dim3(670), dim3(256), 0, stream>>>(s_q, s_k, s_mid);

  // 3. LayerNorm (2056 blocks) + attention (48 blocks, scheduled first)
  ln_attn<<<dim3(2104), dim3(256), 0, stream>>>(mid_bf, ln_g, ln_b, q_bf, k_bf, attn);

  // 4. t = attn . midq
  tk_kernel<<<dim3(512), dim3(256), 0, stream>>>(attn, mid_bf, tbuf);

  // 5. out_pre = t . Wconv
  vproj_kernel<<<dim3(64, 3), dim3(256), 0, stream>>>(tbuf, Wconv, op_bf);

  // 6. out = out_pre @ Wout^T, split-K=4 atomic fp32
  gemm_out_k<<<dim3(4, 6, 4), dim3(256), 0, stream>>>(op_bf, wout_bf, out);
}